// Round 3
// baseline (226.170 us; speedup 1.0000x reference)
//
#include <hip/hip_runtime.h>

#define MAX_SEP 512
#define T_ROWS 1025          // 2*MAX_SEP+1
#define H 160
#define B 4
#define S 256
#define HV 40                // H/4 float4 per h-row
#define TG 257               // ceil(1025/4)
#define ROW_BYTES (H * 4)    // 640 bytes per Y row

typedef float v4f __attribute__((ext_vector_type(4)));

// ---------------------------------------------------------------------------
// Kernel 1: Y[q][t][h] = sum_kk pe_q[t][kk] * W[h][q*H+kk]   (+ bias folded
// into q==0 table). W rows read directly (160 consecutive floats -> dwordx4;
// W = 410 KB, L2-resident). Each thread computes 4 consecutive t per (q,h).
// ---------------------------------------------------------------------------
__global__ __launch_bounds__(256) void compute_y(
        const float* __restrict__ pe0, const float* __restrict__ pe1,
        const float* __restrict__ pe2, const float* __restrict__ pe3,
        const float* __restrict__ W,   const float* __restrict__ bias,
        float* __restrict__ Y) {
    int e = blockIdx.x * 256 + threadIdx.x;       // over (q, tg, h)
    if (e >= 4 * TG * H) return;
    int h  = e % H;
    int tg = (e / H) % TG;
    int q  = e / (H * TG);
    const float* pe = (q == 0) ? pe0 : (q == 1) ? pe1 : (q == 2) ? pe2 : pe3;

    int t0 = tg * 4;
    int t1 = min(t0 + 1, T_ROWS - 1);             // clamp reads; stores guarded
    int t2 = min(t0 + 2, T_ROWS - 1);
    int t3 = min(t0 + 3, T_ROWS - 1);
    const float* p0 = pe + (size_t)t0 * H;
    const float* p1 = pe + (size_t)t1 * H;
    const float* p2 = pe + (size_t)t2 * H;
    const float* p3 = pe + (size_t)t3 * H;
    const float* wrow = W + (size_t)h * (4 * H) + q * H;  // 160 consecutive

    float a0 = 0.f, a1 = 0.f, a2 = 0.f, a3 = 0.f;
#pragma unroll 8
    for (int kk = 0; kk < H; ++kk) {
        float w = wrow[kk];
        a0 = fmaf(p0[kk], w, a0);
        a1 = fmaf(p1[kk], w, a1);
        a2 = fmaf(p2[kk], w, a2);
        a3 = fmaf(p3[kk], w, a3);
    }
    float bb = (q == 0) ? bias[h] : 0.f;
    float* yq = Y + ((size_t)q * T_ROWS + t0) * H + h;    // coalesced over h
    yq[0] = a0 + bb;
    if (t0 + 1 < T_ROWS) yq[H]     = a1 + bb;
    if (t0 + 2 < T_ROWS) yq[2 * H] = a2 + bb;
    if (t0 + 3 < T_ROWS) yq[3 * H] = a3 + bb;
}

// ---------------------------------------------------------------------------
// Kernel 2: out[b,i,j,h] = ReLU(Y0[d_ss]+Y1[d_se]+Y2[d_es]+Y3[d_ee])[h]
// 2 blocks per (b,i) row -> 2048 blocks = 8 blocks/CU x 4 waves = 32 waves/CU
// (max occupancy). Per-block precompute: int4 LDS table of the 4 Y-row byte
// offsets per j (one ds_read_b128 in the hot loop instead of 2 ds_read_b32 +
// index math). Non-temporal dwordx4 stores keep Y L2-resident.
// ---------------------------------------------------------------------------
__global__ __launch_bounds__(256) void gather_add(
        const int* __restrict__ pos_s, const int* __restrict__ pos_e,
        const float* __restrict__ Y, float* __restrict__ out) {
    int blk  = blockIdx.x;            // 0..2047
    int bi   = blk >> 1;              // (b,i) row
    int half = blk & 1;               // which half of the row
    int bb   = bi >> 8;               // / S
    int i    = bi & (S - 1);
    int tid  = threadIdx.x;

    // broadcast loads (same address across all threads)
    int psi = pos_s[bb * S + i];
    int pei = pos_e[bb * S + i];

    __shared__ int4 rows_s[S];        // 4 KB: per-j byte offsets into Y
    {
        int pj_s = pos_s[bb * S + tid];
        int pj_e = pos_e[bb * S + tid];
        int d0 = psi - pj_s + MAX_SEP;            // table 0: ss
        int d1 = psi - pj_e + MAX_SEP;            // table 1: se
        int d2 = pei - pj_s + MAX_SEP;            // table 2: es
        int d3 = pei - pj_e + MAX_SEP;            // table 3: ee
        int4 r;
        r.x = (0 * T_ROWS + d0) * ROW_BYTES;
        r.y = (1 * T_ROWS + d1) * ROW_BYTES;
        r.z = (2 * T_ROWS + d2) * ROW_BYTES;
        r.w = (3 * T_ROWS + d3) * ROW_BYTES;
        rows_s[tid] = r;
    }
    __syncthreads();

    const char* __restrict__ Yb = (const char*)Y;
    v4f* __restrict__ out4 = (v4f*)out + (size_t)bi * (S * HV);
    int start = half * (S * HV / 2);  // 5120 float4 per half, 20 iters of 256

#pragma unroll 4
    for (int it = 0; it < 20; ++it) {
        int base = start + it * 256 + tid;
        int j  = base / HV;           // magic-mul
        int hv = base - j * HV;
        int4 r4 = rows_s[j];          // ds_read_b128, broadcast-heavy
        int hb = hv << 4;
        v4f v0 = *(const v4f*)(Yb + (r4.x + hb));
        v4f v1 = *(const v4f*)(Yb + (r4.y + hb));
        v4f v2 = *(const v4f*)(Yb + (r4.z + hb));
        v4f v3 = *(const v4f*)(Yb + (r4.w + hb));
        v4f s = v0 + v1 + v2 + v3;
        v4f r;
        r.x = fmaxf(s.x, 0.f);
        r.y = fmaxf(s.y, 0.f);
        r.z = fmaxf(s.z, 0.f);
        r.w = fmaxf(s.w, 0.f);
        __builtin_nontemporal_store(r, &out4[base]);   // dwordx4 nt
    }
}

// ---------------------------------------------------------------------------
extern "C" void kernel_launch(void* const* d_in, const int* in_sizes, int n_in,
                              void* d_out, int out_size, void* d_ws, size_t ws_size,
                              hipStream_t stream) {
    const int*   pos_s = (const int*)d_in[0];
    const int*   pos_e = (const int*)d_in[1];
    const float* pe_ss = (const float*)d_in[2];
    const float* pe_se = (const float*)d_in[3];
    const float* pe_es = (const float*)d_in[4];
    const float* pe_ee = (const float*)d_in[5];
    const float* W     = (const float*)d_in[6];
    const float* bias  = (const float*)d_in[7];
    float* out = (float*)d_out;

    float* Y = (float*)d_ws;                        // 4*1025*160*4 = 2.624 MB

    compute_y<<<(4 * TG * H + 255) / 256, 256, 0, stream>>>(
        pe_ss, pe_se, pe_es, pe_ee, W, bias, Y);
    gather_add<<<2 * B * S, 256, 0, stream>>>(pos_s, pos_e, Y, out);
}

// Round 4
// 217.956 us; speedup vs baseline: 1.0377x; 1.0377x over previous
//
#include <hip/hip_runtime.h>

#define MAX_SEP 512
#define T_ROWS 1025          // 2*MAX_SEP+1
#define H 160
#define B 4
#define S 256
#define TG 257               // ceil(1025/4)
#define ROWB 320             // bf16 row bytes (160 * 2)
#define HC 20                // 8-bf16 chunks per row

typedef float v8f __attribute__((ext_vector_type(8)));

// ---------------------------------------------------------------------------
// Kernel 1: Y[q][t][h] = bf16( sum_kk pe_q[t][kk] * W[h][q*H+kk] + bias )
// (bias folded into q==0 table). fp32 accumulate, RTN-even round to bf16.
// ---------------------------------------------------------------------------
__global__ __launch_bounds__(256) void compute_y(
        const float* __restrict__ pe0, const float* __restrict__ pe1,
        const float* __restrict__ pe2, const float* __restrict__ pe3,
        const float* __restrict__ W,   const float* __restrict__ bias,
        unsigned short* __restrict__ Y) {
    int e = blockIdx.x * 256 + threadIdx.x;       // over (q, tg, h)
    if (e >= 4 * TG * H) return;
    int h  = e % H;
    int tg = (e / H) % TG;
    int q  = e / (H * TG);
    const float* pe = (q == 0) ? pe0 : (q == 1) ? pe1 : (q == 2) ? pe2 : pe3;

    int t0 = tg * 4;
    int t1 = min(t0 + 1, T_ROWS - 1);             // clamp reads; stores guarded
    int t2 = min(t0 + 2, T_ROWS - 1);
    int t3 = min(t0 + 3, T_ROWS - 1);
    const float* p0 = pe + (size_t)t0 * H;
    const float* p1 = pe + (size_t)t1 * H;
    const float* p2 = pe + (size_t)t2 * H;
    const float* p3 = pe + (size_t)t3 * H;
    const float* wrow = W + (size_t)h * (4 * H) + q * H;  // 160 consecutive

    float a0 = 0.f, a1 = 0.f, a2 = 0.f, a3 = 0.f;
#pragma unroll 8
    for (int kk = 0; kk < H; ++kk) {
        float w = wrow[kk];
        a0 = fmaf(p0[kk], w, a0);
        a1 = fmaf(p1[kk], w, a1);
        a2 = fmaf(p2[kk], w, a2);
        a3 = fmaf(p3[kk], w, a3);
    }
    float bb = (q == 0) ? bias[h] : 0.f;
    a0 += bb; a1 += bb; a2 += bb; a3 += bb;

    union { float f; unsigned u; } c0, c1, c2, c3;
    c0.f = a0; c1.f = a1; c2.f = a2; c3.f = a3;
    // round-to-nearest-even bf16
    unsigned short r0 = (unsigned short)((c0.u + 0x7FFFu + ((c0.u >> 16) & 1u)) >> 16);
    unsigned short r1 = (unsigned short)((c1.u + 0x7FFFu + ((c1.u >> 16) & 1u)) >> 16);
    unsigned short r2 = (unsigned short)((c2.u + 0x7FFFu + ((c2.u >> 16) & 1u)) >> 16);
    unsigned short r3 = (unsigned short)((c3.u + 0x7FFFu + ((c3.u >> 16) & 1u)) >> 16);

    unsigned short* yq = Y + ((size_t)q * T_ROWS + t0) * H + h;  // coalesced in h
    yq[0] = r0;
    if (t0 + 1 < T_ROWS) yq[H]     = r1;
    if (t0 + 2 < T_ROWS) yq[2 * H] = r2;
    if (t0 + 3 < T_ROWS) yq[3 * H] = r3;
}

// ---------------------------------------------------------------------------
// Kernel 2: out[b,i,j,h] = ReLU(Y0[d_ss]+Y1[d_se]+Y2[d_es]+Y3[d_ee])[h]
// Y is bf16 (1.3 MB -> L2-resident against the write stream). Each lane
// handles 8 consecutive h: 4x16B gather loads, bit-shift cvt to fp32, sum,
// ReLU, 32B coalesced store. 2 blocks/(b,i) row -> 2048 blocks = 32 waves/CU.
// ---------------------------------------------------------------------------
__global__ __launch_bounds__(256) void gather_add(
        const int* __restrict__ pos_s, const int* __restrict__ pos_e,
        const unsigned short* __restrict__ Y, float* __restrict__ out) {
    int blk  = blockIdx.x;            // 0..2047
    int bi   = blk >> 1;              // (b,i) row
    int half = blk & 1;
    int bb   = bi >> 8;               // / S
    int i    = bi & (S - 1);
    int tid  = threadIdx.x;

    int psi = pos_s[bb * S + i];      // broadcast -> scalar loads
    int pei = pos_e[bb * S + i];

    __shared__ int4 rows_s[S];        // per-j byte offsets into bf16 Y
    {
        int pj_s = pos_s[bb * S + tid];
        int pj_e = pos_e[bb * S + tid];
        int4 r;
        r.x = (0 * T_ROWS + psi - pj_s + MAX_SEP) * ROWB;
        r.y = (1 * T_ROWS + psi - pj_e + MAX_SEP) * ROWB;
        r.z = (2 * T_ROWS + pei - pj_s + MAX_SEP) * ROWB;
        r.w = (3 * T_ROWS + pei - pj_e + MAX_SEP) * ROWB;
        rows_s[tid] = r;
    }
    __syncthreads();

    const char* __restrict__ Yb = (const char*)Y;
    float* __restrict__ outp = out + (size_t)bi * (S * H);
    int start = half * (S * HC / 2);  // 2560 chunks per half, 10 iters of 256

#pragma unroll 2
    for (int it = 0; it < 10; ++it) {
        int c  = start + it * 256 + tid;
        int j  = c / HC;              // magic-mul
        int c8 = c - j * HC;
        int4 r4 = rows_s[j];          // ds_read_b128
        int hb = c8 << 4;             // 16 B per 8-bf16 chunk
        uint4 u0 = *(const uint4*)(Yb + (r4.x + hb));
        uint4 u1 = *(const uint4*)(Yb + (r4.y + hb));
        uint4 u2 = *(const uint4*)(Yb + (r4.z + hb));
        uint4 u3 = *(const uint4*)(Yb + (r4.w + hb));

        v8f s;
        const unsigned* a0 = (const unsigned*)&u0;
        const unsigned* a1 = (const unsigned*)&u1;
        const unsigned* a2 = (const unsigned*)&u2;
        const unsigned* a3 = (const unsigned*)&u3;
#pragma unroll
        for (int k = 0; k < 4; ++k) {
            union { unsigned x; float f; } lo0, hi0, lo1, hi1, lo2, hi2, lo3, hi3;
            lo0.x = a0[k] << 16; hi0.x = a0[k] & 0xFFFF0000u;
            lo1.x = a1[k] << 16; hi1.x = a1[k] & 0xFFFF0000u;
            lo2.x = a2[k] << 16; hi2.x = a2[k] & 0xFFFF0000u;
            lo3.x = a3[k] << 16; hi3.x = a3[k] & 0xFFFF0000u;
            float slo = (lo0.f + lo1.f) + (lo2.f + lo3.f);
            float shi = (hi0.f + hi1.f) + (hi2.f + hi3.f);
            s[2 * k]     = fmaxf(slo, 0.f);
            s[2 * k + 1] = fmaxf(shi, 0.f);
        }
        *(v8f*)(outp + (size_t)c * 8) = s;   // 32 B coalesced (2x dwordx4)
    }
}

// ---------------------------------------------------------------------------
extern "C" void kernel_launch(void* const* d_in, const int* in_sizes, int n_in,
                              void* d_out, int out_size, void* d_ws, size_t ws_size,
                              hipStream_t stream) {
    const int*   pos_s = (const int*)d_in[0];
    const int*   pos_e = (const int*)d_in[1];
    const float* pe_ss = (const float*)d_in[2];
    const float* pe_se = (const float*)d_in[3];
    const float* pe_es = (const float*)d_in[4];
    const float* pe_ee = (const float*)d_in[5];
    const float* W     = (const float*)d_in[6];
    const float* bias  = (const float*)d_in[7];
    float* out = (float*)d_out;

    unsigned short* Y = (unsigned short*)d_ws;      // 4*1025*160*2 = 1.312 MB

    compute_y<<<(4 * TG * H + 255) / 256, 256, 0, stream>>>(
        pe_ss, pe_se, pe_es, pe_ee, W, bias, Y);
    gather_add<<<2 * B * S, 256, 0, stream>>>(pos_s, pos_e, Y, out);
}

// Round 5
// 207.974 us; speedup vs baseline: 1.0875x; 1.0480x over previous
//
#include <hip/hip_runtime.h>

#define MAX_SEP 512
#define T_ROWS 1025          // 2*MAX_SEP+1
#define H 160
#define B 4
#define S 256
#define TG 257               // ceil(1025/4)
#define ROWB 320             // bf16 row bytes (160 * 2)
#define HC 20                // 8-bf16 chunks per row

typedef float v8f __attribute__((ext_vector_type(8)));

// ---------------------------------------------------------------------------
// Kernel A: Wt[q][kk][h] = W[h][q*H+kk]. Makes compute_y's inner-loop weight
// read WAVE-coalesced (lane<->h, consecutive addresses). Reading W directly
// in compute_y is per-lane-contiguous but per-wave-strided by 2560 B: every
// load instr touches 64 cache lines -> ~40 us. This transpose costs ~1 us.
// ---------------------------------------------------------------------------
__global__ __launch_bounds__(256) void transpose_w(const float* __restrict__ W,
                                                   float* __restrict__ Wt) {
    int g = blockIdx.x * 256 + threadIdx.x;       // 4*H*H = 102400
    if (g >= 4 * H * H) return;
    int h  = g % H;
    int kk = (g / H) % H;
    int q  = g / (H * H);
    Wt[g] = W[h * (4 * H) + q * H + kk];          // write coalesced over h
}

// ---------------------------------------------------------------------------
// Kernel B: Y[q][t][h] = bf16( sum_kk pe_q[t][kk] * Wt[q][kk][h] + bias )
// (bias folded into q==0 table). fp32 accumulate, RTN-even round to bf16.
// Weight loads: lane<->h -> 256 B coalesced per instr. pe loads: wave-uniform
// (broadcast). 4 consecutive t per thread amortize the weight stream.
// ---------------------------------------------------------------------------
__global__ __launch_bounds__(256) void compute_y(
        const float* __restrict__ pe0, const float* __restrict__ pe1,
        const float* __restrict__ pe2, const float* __restrict__ pe3,
        const float* __restrict__ Wt,  const float* __restrict__ bias,
        unsigned short* __restrict__ Y) {
    int e = blockIdx.x * 256 + threadIdx.x;       // over (q, tg, h)
    if (e >= 4 * TG * H) return;
    int h  = e % H;
    int tg = (e / H) % TG;
    int q  = e / (H * TG);
    const float* pe = (q == 0) ? pe0 : (q == 1) ? pe1 : (q == 2) ? pe2 : pe3;

    int t0 = tg * 4;
    int t1 = min(t0 + 1, T_ROWS - 1);             // clamp reads; stores guarded
    int t2 = min(t0 + 2, T_ROWS - 1);
    int t3 = min(t0 + 3, T_ROWS - 1);
    const float* p0 = pe + (size_t)t0 * H;
    const float* p1 = pe + (size_t)t1 * H;
    const float* p2 = pe + (size_t)t2 * H;
    const float* p3 = pe + (size_t)t3 * H;
    const float* wt = Wt + (size_t)q * H * H + h; // stride H over kk; coalesced in h

    float a0 = 0.f, a1 = 0.f, a2 = 0.f, a3 = 0.f;
#pragma unroll 8
    for (int kk = 0; kk < H; ++kk) {
        float w = wt[(size_t)kk * H];
        a0 = fmaf(p0[kk], w, a0);
        a1 = fmaf(p1[kk], w, a1);
        a2 = fmaf(p2[kk], w, a2);
        a3 = fmaf(p3[kk], w, a3);
    }
    float bb = (q == 0) ? bias[h] : 0.f;
    a0 += bb; a1 += bb; a2 += bb; a3 += bb;

    union { float f; unsigned u; } c0, c1, c2, c3;
    c0.f = a0; c1.f = a1; c2.f = a2; c3.f = a3;
    // round-to-nearest-even bf16
    unsigned short r0 = (unsigned short)((c0.u + 0x7FFFu + ((c0.u >> 16) & 1u)) >> 16);
    unsigned short r1 = (unsigned short)((c1.u + 0x7FFFu + ((c1.u >> 16) & 1u)) >> 16);
    unsigned short r2 = (unsigned short)((c2.u + 0x7FFFu + ((c2.u >> 16) & 1u)) >> 16);
    unsigned short r3 = (unsigned short)((c3.u + 0x7FFFu + ((c3.u >> 16) & 1u)) >> 16);

    unsigned short* yq = Y + ((size_t)q * T_ROWS + t0) * H + h;  // coalesced in h
    yq[0] = r0;
    if (t0 + 1 < T_ROWS) yq[H]     = r1;
    if (t0 + 2 < T_ROWS) yq[2 * H] = r2;
    if (t0 + 3 < T_ROWS) yq[3 * H] = r3;
}

// ---------------------------------------------------------------------------
// Kernel C: out[b,i,j,h] = ReLU(Y0[d_ss]+Y1[d_se]+Y2[d_es]+Y3[d_ee])[h]
// Y is bf16 (1.3 MB). Each lane handles 8 consecutive h: 4x16B gather loads,
// bit-shift cvt to fp32, sum, ReLU, 32B coalesced store. 2 blocks per (b,i)
// row -> 2048 blocks = 8 blocks/CU x 4 waves = 32 waves/CU (max occupancy).
// Per-block int4 LDS table of the 4 Y-row byte offsets per j.
// ---------------------------------------------------------------------------
__global__ __launch_bounds__(256) void gather_add(
        const int* __restrict__ pos_s, const int* __restrict__ pos_e,
        const unsigned short* __restrict__ Y, float* __restrict__ out) {
    int blk  = blockIdx.x;            // 0..2047
    int bi   = blk >> 1;              // (b,i) row
    int half = blk & 1;
    int bb   = bi >> 8;               // / S
    int i    = bi & (S - 1);
    int tid  = threadIdx.x;

    int psi = pos_s[bb * S + i];      // broadcast -> scalar loads
    int pei = pos_e[bb * S + i];

    __shared__ int4 rows_s[S];        // per-j byte offsets into bf16 Y
    {
        int pj_s = pos_s[bb * S + tid];
        int pj_e = pos_e[bb * S + tid];
        int4 r;
        r.x = (0 * T_ROWS + psi - pj_s + MAX_SEP) * ROWB;
        r.y = (1 * T_ROWS + psi - pj_e + MAX_SEP) * ROWB;
        r.z = (2 * T_ROWS + pei - pj_s + MAX_SEP) * ROWB;
        r.w = (3 * T_ROWS + pei - pj_e + MAX_SEP) * ROWB;
        rows_s[tid] = r;
    }
    __syncthreads();

    const char* __restrict__ Yb = (const char*)Y;
    float* __restrict__ outp = out + (size_t)bi * (S * H);
    int start = half * (S * HC / 2);  // 2560 chunks per half, 10 iters of 256

#pragma unroll 2
    for (int it = 0; it < 10; ++it) {
        int c  = start + it * 256 + tid;
        int j  = c / HC;              // magic-mul
        int c8 = c - j * HC;
        int4 r4 = rows_s[j];          // ds_read_b128
        int hb = c8 << 4;             // 16 B per 8-bf16 chunk
        uint4 u0 = *(const uint4*)(Yb + (r4.x + hb));
        uint4 u1 = *(const uint4*)(Yb + (r4.y + hb));
        uint4 u2 = *(const uint4*)(Yb + (r4.z + hb));
        uint4 u3 = *(const uint4*)(Yb + (r4.w + hb));

        v8f s;
        const unsigned* a0 = (const unsigned*)&u0;
        const unsigned* a1 = (const unsigned*)&u1;
        const unsigned* a2 = (const unsigned*)&u2;
        const unsigned* a3 = (const unsigned*)&u3;
#pragma unroll
        for (int k = 0; k < 4; ++k) {
            union { unsigned x; float f; } lo0, hi0, lo1, hi1, lo2, hi2, lo3, hi3;
            lo0.x = a0[k] << 16; hi0.x = a0[k] & 0xFFFF0000u;
            lo1.x = a1[k] << 16; hi1.x = a1[k] & 0xFFFF0000u;
            lo2.x = a2[k] << 16; hi2.x = a2[k] & 0xFFFF0000u;
            lo3.x = a3[k] << 16; hi3.x = a3[k] & 0xFFFF0000u;
            float slo = (lo0.f + lo1.f) + (lo2.f + lo3.f);
            float shi = (hi0.f + hi1.f) + (hi2.f + hi3.f);
            s[2 * k]     = fmaxf(slo, 0.f);
            s[2 * k + 1] = fmaxf(shi, 0.f);
        }
        *(v8f*)(outp + (size_t)c * 8) = s;   // 32 B coalesced (2x dwordx4)
    }
}

// ---------------------------------------------------------------------------
extern "C" void kernel_launch(void* const* d_in, const int* in_sizes, int n_in,
                              void* d_out, int out_size, void* d_ws, size_t ws_size,
                              hipStream_t stream) {
    const int*   pos_s = (const int*)d_in[0];
    const int*   pos_e = (const int*)d_in[1];
    const float* pe_ss = (const float*)d_in[2];
    const float* pe_se = (const float*)d_in[3];
    const float* pe_es = (const float*)d_in[4];
    const float* pe_ee = (const float*)d_in[5];
    const float* W     = (const float*)d_in[6];
    const float* bias  = (const float*)d_in[7];
    float* out = (float*)d_out;

    // workspace: Wt fp32 [4*H*H] (409,600 B) then Y bf16 (1,312,000 B)
    float* Wt = (float*)d_ws;
    unsigned short* Y = (unsigned short*)(Wt + 4 * H * H);

    transpose_w<<<(4 * H * H + 255) / 256, 256, 0, stream>>>(W, Wt);
    compute_y<<<(4 * TG * H + 255) / 256, 256, 0, stream>>>(
        pe_ss, pe_se, pe_es, pe_ee, Wt, bias, Y);
    gather_add<<<2 * B * S, 256, 0, stream>>>(pos_s, pos_e, Y, out);
}